// Round 6
// baseline (457.232 us; speedup 1.0000x reference)
//
#include <hip/hip_runtime.h>
#include <stdint.h>

#define N_NODES 100000
#define N_EDGES 800000
#define D 128

typedef _Float16 f16x8 __attribute__((ext_vector_type(8)));
typedef float f32x4 __attribute__((ext_vector_type(4)));

// ---------------- CSR build ----------------

__global__ void hist_rank(const int* __restrict__ dst, int* __restrict__ cnt,
                          int* __restrict__ rank) {
    int e = blockIdx.x * blockDim.x + threadIdx.x;
    if (e < N_EDGES) rank[e] = atomicAdd(&cnt[dst[e]], 1);
}

// single-block exclusive scan of cnt[0..N) -> offsets[0..N], 1024 threads x 98
__global__ __launch_bounds__(1024) void scan_one(const int* __restrict__ cnt,
                                                 int* __restrict__ offsets) {
    __shared__ int wsum[16];
    __shared__ int wpre[16];
    const int t = threadIdx.x;
    const int lane = t & 63;
    const int wv = t >> 6;
    const int base = t * 98;
    int s = 0;
    for (int i = 0; i < 98; ++i) {
        int idx = base + i;
        if (idx < N_NODES) s += cnt[idx];
    }
    int incl = s;
    for (int off = 1; off < 64; off <<= 1) {
        int n = __shfl_up(incl, off, 64);
        if (lane >= off) incl += n;
    }
    if (lane == 63) wsum[wv] = incl;
    __syncthreads();
    if (t < 16) {
        int ws_ = wsum[t];
        int inc2 = ws_;
        for (int off = 1; off < 16; off <<= 1) {
            int n = __shfl_up(inc2, off, 64);
            if (t >= off) inc2 += n;
        }
        wpre[t] = inc2 - ws_;
    }
    __syncthreads();
    int run = wpre[wv] + (incl - s);  // exclusive prefix for this thread
    for (int i = 0; i < 98; ++i) {
        int idx = base + i;
        if (idx < N_NODES) {
            offsets[idx] = run;
            run += cnt[idx];
        }
    }
    if (t == 1023) offsets[N_NODES] = run;  // == N_EDGES
}

__global__ void scatter2(const int* __restrict__ src, const int* __restrict__ dst,
                         const int* __restrict__ offsets, const int* __restrict__ rank,
                         int* __restrict__ esrc) {
    int e = blockIdx.x * blockDim.x + threadIdx.x;
    if (e < N_EDGES) esrc[offsets[dst[e]] + rank[e]] = src[e];
}

// ---------------- register-B MFMA GEMM (no LDS, no barriers) ----------------
// blockIdx.x&1==0: pre = x@Ws + b -> out (fp32);  ==1: y2 = x@Wn -> ws (f16)
// Each wave: B-fragments for a 64-col half in registers; grid-stride over
// 16-row strips of x; A loaded straight from global (f32->f16 in-register).
// Fragment layout (verified round 5): A lane row=l&15, k=(l>>4)*8+j;
// B lane col=l&15, k=(l>>4)*8+j; C col=l&15, row=(l>>4)*4+i.
__global__ __launch_bounds__(256) void gemm_reg(const float* __restrict__ x,
                                                const float* __restrict__ Ws,
                                                const float* __restrict__ Wn,
                                                const float* __restrict__ bias,
                                                float* __restrict__ pre,
                                                _Float16* __restrict__ y2) {
    const int half = blockIdx.x & 1;
    const int bid = blockIdx.x >> 1;
    const int nb = gridDim.x >> 1;
    const int tid = threadIdx.x;
    const int w = tid >> 6;        // wave 0..3
    const int lane = tid & 63;
    const int lr = lane & 15;
    const int lk = (lane >> 4) * 8;   // k-offset within 32-k slice
    const int wc = w & 1;             // col half 0/1
    const int ws_ = w >> 1;           // strip sub-index 0/1

    const float* __restrict__ W = half ? Wn : Ws;

    // B fragments: bfrag[ks][fc] covers k = ks*32+lk..+7, col = wc*64+fc*16+lr
    f16x8 bfrag[4][4];
#pragma unroll
    for (int ks = 0; ks < 4; ++ks) {
#pragma unroll
        for (int fc = 0; fc < 4; ++fc) {
            const int col = wc * 64 + fc * 16 + lr;
            const int kb = ks * 32 + lk;
            f16x8 h;
#pragma unroll
            for (int j = 0; j < 8; ++j) h[j] = (_Float16)W[(long)(kb + j) * D + col];
            bfrag[ks][fc] = h;
        }
    }
    float bv[4];
    if (half == 0) {
#pragma unroll
        for (int fc = 0; fc < 4; ++fc) bv[fc] = bias[wc * 64 + fc * 16 + lr];
    }

    const int nstrip = N_NODES / 16;  // 6250, exact
    for (int s = bid * 2 + ws_; s < nstrip; s += nb * 2) {
        const float* __restrict__ xr = &x[(long)(s * 16 + lr) * D];
        f32x4 a0[4], a1[4];
#pragma unroll
        for (int ks = 0; ks < 4; ++ks) {
            a0[ks] = *(const f32x4*)&xr[ks * 32 + lk];
            a1[ks] = *(const f32x4*)&xr[ks * 32 + lk + 4];
        }
        f32x4 acc[4];
#pragma unroll
        for (int fc = 0; fc < 4; ++fc) acc[fc] = (f32x4){0.f, 0.f, 0.f, 0.f};
#pragma unroll
        for (int ks = 0; ks < 4; ++ks) {
            f16x8 af;
#pragma unroll
            for (int j = 0; j < 4; ++j) {
                af[j] = (_Float16)a0[ks][j];
                af[4 + j] = (_Float16)a1[ks][j];
            }
#pragma unroll
            for (int fc = 0; fc < 4; ++fc)
                acc[fc] = __builtin_amdgcn_mfma_f32_16x16x32_f16(af, bfrag[ks][fc],
                                                                 acc[fc], 0, 0, 0);
        }
        const int rb = s * 16 + (lane >> 4) * 4;
        if (half == 0) {
#pragma unroll
            for (int fc = 0; fc < 4; ++fc) {
                const int col = wc * 64 + fc * 16 + lr;
#pragma unroll
                for (int i = 0; i < 4; ++i)
                    pre[(long)(rb + i) * D + col] = acc[fc][i] + bv[fc];
            }
        } else {
#pragma unroll
            for (int fc = 0; fc < 4; ++fc) {
                const int col = wc * 64 + fc * 16 + lr;
#pragma unroll
                for (int i = 0; i < 4; ++i)
                    y2[(long)(rb + i) * D + col] = (_Float16)acc[fc][i];
            }
        }
    }
}

// ---------------- fused aggregate + epilogue ----------------
// out[n] = relu(pre[n] + mean_{e: dst=n} y2[src[e]])   (in-place, pre==out)
__global__ __launch_bounds__(256) void agg_ep(const _Float16* __restrict__ y2,
                                              const int* __restrict__ offsets,
                                              const int* __restrict__ esrc,
                                              float* __restrict__ out) {
    __shared__ float red[16][128];
    const int n = blockIdx.x;
    const int slot = threadIdx.x >> 4;   // 0..15
    const int c8 = threadIdx.x & 15;     // half8 col group
    const int s = offsets[n];
    const int e = offsets[n + 1];
    float a[8] = {0.f, 0.f, 0.f, 0.f, 0.f, 0.f, 0.f, 0.f};
    for (int j = s + slot; j < e; j += 16) {
        int sn = esrc[j];
        f16x8 v = *(const f16x8*)&y2[(long)sn * D + c8 * 8];
#pragma unroll
        for (int i = 0; i < 8; ++i) a[i] += (float)v[i];
    }
    *(float4*)&red[slot][c8 * 8] = make_float4(a[0], a[1], a[2], a[3]);
    *(float4*)&red[slot][c8 * 8 + 4] = make_float4(a[4], a[5], a[6], a[7]);
    __syncthreads();
    if (threadIdx.x < 128) {
        const int d = threadIdx.x;
        float ssum = 0.f;
#pragma unroll
        for (int r = 0; r < 16; ++r) ssum += red[r][d];
        int deg = e - s;
        float v = out[(long)n * D + d];
        if (deg > 0) v += ssum / (float)deg;
        out[(long)n * D + d] = fmaxf(v, 0.f);
    }
}

// ---------------- launch ----------------

extern "C" void kernel_launch(void* const* d_in, const int* in_sizes, int n_in,
                              void* d_out, int out_size, void* d_ws, size_t ws_size,
                              hipStream_t stream) {
    const float* x  = (const float*)d_in[0];
    const int* src  = (const int*)d_in[1];
    const int* dst  = (const int*)d_in[2];
    const float* Ws = (const float*)d_in[3];
    const float* Wn = (const float*)d_in[4];
    const float* b  = (const float*)d_in[5];
    float* out = (float*)d_out;

    int* cnt     = (int*)d_ws;                 // N
    int* offsets = cnt + N_NODES;              // N+1
    int* rank    = offsets + N_NODES + 1;      // E
    int* esrc    = rank + N_EDGES;             // E
    uintptr_t p = (uintptr_t)(esrc + N_EDGES);
    p = (p + 255) & ~(uintptr_t)255;
    _Float16* y2 = (_Float16*)p;               // N*D f16

    hipMemsetAsync(cnt, 0, N_NODES * sizeof(int), stream);
    hist_rank<<<(N_EDGES + 255) / 256, 256, 0, stream>>>(dst, cnt, rank);
    scan_one<<<1, 1024, 0, stream>>>(cnt, offsets);
    scatter2<<<(N_EDGES + 255) / 256, 256, 0, stream>>>(src, dst, offsets, rank, esrc);
    gemm_reg<<<2048, 256, 0, stream>>>(x, Ws, Wn, b, out, y2);
    agg_ep<<<N_NODES, 256, 0, stream>>>(y2, offsets, esrc, out);
}

// Round 7
// 279.995 us; speedup vs baseline: 1.6330x; 1.6330x over previous
//
#include <hip/hip_runtime.h>
#include <stdint.h>

#define N_NODES 100000
#define N_EDGES 800000
#define D 128

typedef _Float16 f16x8 __attribute__((ext_vector_type(8)));
typedef float f32x4 __attribute__((ext_vector_type(4)));

// ---------------- CSR build ----------------

__global__ void hist_rank(const int* __restrict__ dst, int* __restrict__ cnt,
                          int* __restrict__ rank) {
    int e = blockIdx.x * blockDim.x + threadIdx.x;
    if (e < N_EDGES) rank[e] = atomicAdd(&cnt[dst[e]], 1);
}

// 1024 elements per block, 256 threads x 4 each. Local exclusive scan into
// offsets[i], block total into bs[blockIdx.x].
__global__ void scan_local(const int* __restrict__ cnt, int* __restrict__ offsets,
                           int* __restrict__ bs) {
    __shared__ int sdata[256];
    const int t = threadIdx.x;
    const int base = blockIdx.x * 1024 + t * 4;
    int v[4];
    int s = 0;
#pragma unroll
    for (int j = 0; j < 4; ++j) {
        int i = base + j;
        v[j] = (i < N_NODES) ? cnt[i] : 0;
        s += v[j];
    }
    sdata[t] = s;
    __syncthreads();
    int incl = s;
    for (int off = 1; off < 256; off <<= 1) {
        int add = (t >= off) ? sdata[t - off] : 0;
        __syncthreads();
        incl += add;
        sdata[t] = incl;
        __syncthreads();
    }
    int run = incl - s;
#pragma unroll
    for (int j = 0; j < 4; ++j) {
        int i = base + j;
        if (i < N_NODES) offsets[i] = run;
        run += v[j];
    }
    if (t == 255) bs[blockIdx.x] = incl;
}

// one wave scans the (<=128) block sums
__global__ void scan_block2(int* __restrict__ bs, int* __restrict__ offsets, int nblk) {
    int t = threadIdx.x;  // 0..63
    int v0 = (2 * t < nblk) ? bs[2 * t] : 0;
    int v1 = (2 * t + 1 < nblk) ? bs[2 * t + 1] : 0;
    int s = v0 + v1;
    int incl = s;
    for (int off = 1; off < 64; off <<= 1) {
        int n = __shfl_up(incl, off, 64);
        if (t >= off) incl += n;
    }
    int excl = incl - s;
    if (2 * t < nblk) bs[2 * t] = excl;
    if (2 * t + 1 < nblk) bs[2 * t + 1] = excl + v0;
    if (t == 63) offsets[N_NODES] = incl;  // == N_EDGES
}

__global__ void scan_add(int* __restrict__ offsets, const int* __restrict__ bs) {
    const int t = threadIdx.x;
    const int base = blockIdx.x * 1024 + t * 4;
    const int add = bs[blockIdx.x];
#pragma unroll
    for (int j = 0; j < 4; ++j) {
        int i = base + j;
        if (i < N_NODES) offsets[i] += add;
    }
}

__global__ void scatter2(const int* __restrict__ src, const int* __restrict__ dst,
                         const int* __restrict__ offsets, const int* __restrict__ rank,
                         int* __restrict__ esrc) {
    int e = blockIdx.x * blockDim.x + threadIdx.x;
    if (e < N_EDGES) esrc[offsets[dst[e]] + rank[e]] = src[e];
}

// ---------------- register-B MFMA GEMM (no LDS, no barriers) ----------------
// blockIdx.x&1==0: pre = x@Ws + b -> out (fp32);  ==1: y2 = x@Wn -> ws (f16)
__global__ __launch_bounds__(256) void gemm_reg(const float* __restrict__ x,
                                                const float* __restrict__ Ws,
                                                const float* __restrict__ Wn,
                                                const float* __restrict__ bias,
                                                float* __restrict__ pre,
                                                _Float16* __restrict__ y2) {
    const int half = blockIdx.x & 1;
    const int bid = blockIdx.x >> 1;
    const int nb = gridDim.x >> 1;
    const int tid = threadIdx.x;
    const int w = tid >> 6;        // wave 0..3
    const int lane = tid & 63;
    const int lr = lane & 15;
    const int lk = (lane >> 4) * 8;   // k-offset within 32-k slice
    const int wc = w & 1;             // col half 0/1
    const int ws_ = w >> 1;           // strip sub-index 0/1

    const float* __restrict__ W = half ? Wn : Ws;

    // B fragments: bfrag[ks][fc] covers k = ks*32+lk..+7, col = wc*64+fc*16+lr
    f16x8 bfrag[4][4];
#pragma unroll
    for (int ks = 0; ks < 4; ++ks) {
#pragma unroll
        for (int fc = 0; fc < 4; ++fc) {
            const int col = wc * 64 + fc * 16 + lr;
            const int kb = ks * 32 + lk;
            f16x8 h;
#pragma unroll
            for (int j = 0; j < 8; ++j) h[j] = (_Float16)W[(long)(kb + j) * D + col];
            bfrag[ks][fc] = h;
        }
    }
    float bv[4];
    if (half == 0) {
#pragma unroll
        for (int fc = 0; fc < 4; ++fc) bv[fc] = bias[wc * 64 + fc * 16 + lr];
    }

    const int nstrip = N_NODES / 16;  // 6250, exact
    for (int s = bid * 2 + ws_; s < nstrip; s += nb * 2) {
        const float* __restrict__ xr = &x[(long)(s * 16 + lr) * D];
        f32x4 a0[4], a1[4];
#pragma unroll
        for (int ks = 0; ks < 4; ++ks) {
            a0[ks] = *(const f32x4*)&xr[ks * 32 + lk];
            a1[ks] = *(const f32x4*)&xr[ks * 32 + lk + 4];
        }
        f32x4 acc[4];
#pragma unroll
        for (int fc = 0; fc < 4; ++fc) acc[fc] = (f32x4){0.f, 0.f, 0.f, 0.f};
#pragma unroll
        for (int ks = 0; ks < 4; ++ks) {
            f16x8 af;
#pragma unroll
            for (int j = 0; j < 4; ++j) {
                af[j] = (_Float16)a0[ks][j];
                af[4 + j] = (_Float16)a1[ks][j];
            }
#pragma unroll
            for (int fc = 0; fc < 4; ++fc)
                acc[fc] = __builtin_amdgcn_mfma_f32_16x16x32_f16(af, bfrag[ks][fc],
                                                                 acc[fc], 0, 0, 0);
        }
        const int rb = s * 16 + (lane >> 4) * 4;
        if (half == 0) {
#pragma unroll
            for (int fc = 0; fc < 4; ++fc) {
                const int col = wc * 64 + fc * 16 + lr;
#pragma unroll
                for (int i = 0; i < 4; ++i)
                    pre[(long)(rb + i) * D + col] = acc[fc][i] + bv[fc];
            }
        } else {
#pragma unroll
            for (int fc = 0; fc < 4; ++fc) {
                const int col = wc * 64 + fc * 16 + lr;
#pragma unroll
                for (int i = 0; i < 4; ++i)
                    y2[(long)(rb + i) * D + col] = (_Float16)acc[fc][i];
            }
        }
    }
}

// ---------------- fused aggregate + epilogue ----------------
// out[n] = relu(pre[n] + mean_{e: dst=n} y2[src[e]])   (in-place, pre==out)
__global__ __launch_bounds__(256) void agg_ep(const _Float16* __restrict__ y2,
                                              const int* __restrict__ offsets,
                                              const int* __restrict__ esrc,
                                              float* __restrict__ out) {
    __shared__ float red[16][128];
    const int n = blockIdx.x;
    const int slot = threadIdx.x >> 4;   // 0..15
    const int c8 = threadIdx.x & 15;     // half8 col group
    const int s = offsets[n];
    const int e = offsets[n + 1];
    float a[8] = {0.f, 0.f, 0.f, 0.f, 0.f, 0.f, 0.f, 0.f};
    for (int j = s + slot; j < e; j += 16) {
        int sn = esrc[j];
        f16x8 v = *(const f16x8*)&y2[(long)sn * D + c8 * 8];
#pragma unroll
        for (int i = 0; i < 8; ++i) a[i] += (float)v[i];
    }
    *(float4*)&red[slot][c8 * 8] = make_float4(a[0], a[1], a[2], a[3]);
    *(float4*)&red[slot][c8 * 8 + 4] = make_float4(a[4], a[5], a[6], a[7]);
    __syncthreads();
    if (threadIdx.x < 128) {
        const int d = threadIdx.x;
        float ssum = 0.f;
#pragma unroll
        for (int r = 0; r < 16; ++r) ssum += red[r][d];
        int deg = e - s;
        float v = out[(long)n * D + d];
        if (deg > 0) v += ssum / (float)deg;
        out[(long)n * D + d] = fmaxf(v, 0.f);
    }
}

// ---------------- launch ----------------

extern "C" void kernel_launch(void* const* d_in, const int* in_sizes, int n_in,
                              void* d_out, int out_size, void* d_ws, size_t ws_size,
                              hipStream_t stream) {
    const float* x  = (const float*)d_in[0];
    const int* src  = (const int*)d_in[1];
    const int* dst  = (const int*)d_in[2];
    const float* Ws = (const float*)d_in[3];
    const float* Wn = (const float*)d_in[4];
    const float* b  = (const float*)d_in[5];
    float* out = (float*)d_out;

    int* cnt     = (int*)d_ws;                 // N
    int* offsets = cnt + N_NODES;              // N+1
    int* bs      = offsets + N_NODES + 1;      // 128
    int* rank    = bs + 128;                   // E
    int* esrc    = rank + N_EDGES;             // E
    uintptr_t p = (uintptr_t)(esrc + N_EDGES);
    p = (p + 255) & ~(uintptr_t)255;
    _Float16* y2 = (_Float16*)p;               // N*D f16

    const int nblk_scan = (N_NODES + 1023) / 1024;  // 98

    hipMemsetAsync(cnt, 0, N_NODES * sizeof(int), stream);
    hist_rank<<<(N_EDGES + 255) / 256, 256, 0, stream>>>(dst, cnt, rank);
    scan_local<<<nblk_scan, 256, 0, stream>>>(cnt, offsets, bs);
    scan_block2<<<1, 64, 0, stream>>>(bs, offsets, nblk_scan);
    scan_add<<<nblk_scan, 256, 0, stream>>>(offsets, bs);
    scatter2<<<(N_EDGES + 255) / 256, 256, 0, stream>>>(src, dst, offsets, rank, esrc);
    gemm_reg<<<2048, 256, 0, stream>>>(x, Ws, Wn, b, out, y2);
    agg_ep<<<N_NODES, 256, 0, stream>>>(y2, offsets, esrc, out);
}

// Round 9
// 252.208 us; speedup vs baseline: 1.8129x; 1.1102x over previous
//
#include <hip/hip_runtime.h>
#include <stdint.h>

#define N_NODES 100000
#define N_EDGES 800000
#define D 128

typedef _Float16 f16x8 __attribute__((ext_vector_type(8)));
typedef float f32x4 __attribute__((ext_vector_type(4)));

// ---------------- CSR build ----------------

__global__ void hist_rank(const int* __restrict__ dst, int* __restrict__ cnt,
                          int* __restrict__ rank) {
    int e = blockIdx.x * blockDim.x + threadIdx.x;
    if (e < N_EDGES) rank[e] = atomicAdd(&cnt[dst[e]], 1);
}

__global__ void scan_local(const int* __restrict__ cnt, int* __restrict__ offsets,
                           int* __restrict__ bs) {
    __shared__ int sdata[256];
    const int t = threadIdx.x;
    const int base = blockIdx.x * 1024 + t * 4;
    int v[4];
    int s = 0;
#pragma unroll
    for (int j = 0; j < 4; ++j) {
        int i = base + j;
        v[j] = (i < N_NODES) ? cnt[i] : 0;
        s += v[j];
    }
    sdata[t] = s;
    __syncthreads();
    int incl = s;
    for (int off = 1; off < 256; off <<= 1) {
        int add = (t >= off) ? sdata[t - off] : 0;
        __syncthreads();
        incl += add;
        sdata[t] = incl;
        __syncthreads();
    }
    int run = incl - s;
#pragma unroll
    for (int j = 0; j < 4; ++j) {
        int i = base + j;
        if (i < N_NODES) offsets[i] = run;
        run += v[j];
    }
    if (t == 255) bs[blockIdx.x] = incl;
}

__global__ void scan_block2(int* __restrict__ bs, int* __restrict__ offsets, int nblk) {
    int t = threadIdx.x;  // 0..63
    int v0 = (2 * t < nblk) ? bs[2 * t] : 0;
    int v1 = (2 * t + 1 < nblk) ? bs[2 * t + 1] : 0;
    int s = v0 + v1;
    int incl = s;
    for (int off = 1; off < 64; off <<= 1) {
        int n = __shfl_up(incl, off, 64);
        if (t >= off) incl += n;
    }
    int excl = incl - s;
    if (2 * t < nblk) bs[2 * t] = excl;
    if (2 * t + 1 < nblk) bs[2 * t + 1] = excl + v0;
    if (t == 63) offsets[N_NODES] = incl;
}

__global__ void scan_add(int* __restrict__ offsets, const int* __restrict__ bs) {
    const int t = threadIdx.x;
    const int base = blockIdx.x * 1024 + t * 4;
    const int add = bs[blockIdx.x];
#pragma unroll
    for (int j = 0; j < 4; ++j) {
        int i = base + j;
        if (i < N_NODES) offsets[i] += add;
    }
}

__global__ void scatter2(const int* __restrict__ src, const int* __restrict__ dst,
                         const int* __restrict__ offsets, const int* __restrict__ rank,
                         int* __restrict__ esrc) {
    int e = blockIdx.x * blockDim.x + threadIdx.x;
    if (e < N_EDGES) esrc[offsets[dst[e]] + rank[e]] = src[e];
}

// ---------------- register-B MFMA GEMM (no LDS, no barriers) ----------------
// blockIdx.x&1==0: pre = x@Ws + b -> out (fp32);  ==1: y2 = x@Wn -> ws (f16)
__global__ __launch_bounds__(256) void gemm_reg(const float* __restrict__ x,
                                                const float* __restrict__ Ws,
                                                const float* __restrict__ Wn,
                                                const float* __restrict__ bias,
                                                float* __restrict__ pre,
                                                _Float16* __restrict__ y2) {
    const int half = blockIdx.x & 1;
    const int bid = blockIdx.x >> 1;
    const int nb = gridDim.x >> 1;
    const int tid = threadIdx.x;
    const int w = tid >> 6;
    const int lane = tid & 63;
    const int lr = lane & 15;
    const int lk = (lane >> 4) * 8;
    const int wc = w & 1;
    const int ws_ = w >> 1;

    const float* __restrict__ W = half ? Wn : Ws;

    f16x8 bfrag[4][4];
#pragma unroll
    for (int ks = 0; ks < 4; ++ks) {
#pragma unroll
        for (int fc = 0; fc < 4; ++fc) {
            const int col = wc * 64 + fc * 16 + lr;
            const int kb = ks * 32 + lk;
            f16x8 h;
#pragma unroll
            for (int j = 0; j < 8; ++j) h[j] = (_Float16)W[(long)(kb + j) * D + col];
            bfrag[ks][fc] = h;
        }
    }
    float bv[4];
    if (half == 0) {
#pragma unroll
        for (int fc = 0; fc < 4; ++fc) bv[fc] = bias[wc * 64 + fc * 16 + lr];
    }

    const int nstrip = N_NODES / 16;  // 6250, exact
    for (int s = bid * 2 + ws_; s < nstrip; s += nb * 2) {
        const float* __restrict__ xr = &x[(long)(s * 16 + lr) * D];
        f32x4 a0[4], a1[4];
#pragma unroll
        for (int ks = 0; ks < 4; ++ks) {
            a0[ks] = *(const f32x4*)&xr[ks * 32 + lk];
            a1[ks] = *(const f32x4*)&xr[ks * 32 + lk + 4];
        }
        f32x4 acc[4];
#pragma unroll
        for (int fc = 0; fc < 4; ++fc) acc[fc] = (f32x4){0.f, 0.f, 0.f, 0.f};
#pragma unroll
        for (int ks = 0; ks < 4; ++ks) {
            f16x8 af;
#pragma unroll
            for (int j = 0; j < 4; ++j) {
                af[j] = (_Float16)a0[ks][j];
                af[4 + j] = (_Float16)a1[ks][j];
            }
#pragma unroll
            for (int fc = 0; fc < 4; ++fc)
                acc[fc] = __builtin_amdgcn_mfma_f32_16x16x32_f16(af, bfrag[ks][fc],
                                                                 acc[fc], 0, 0, 0);
        }
        const int rb = s * 16 + (lane >> 4) * 4;
        if (half == 0) {
#pragma unroll
            for (int fc = 0; fc < 4; ++fc) {
                const int col = wc * 64 + fc * 16 + lr;
#pragma unroll
                for (int i = 0; i < 4; ++i)
                    pre[(long)(rb + i) * D + col] = acc[fc][i] + bv[fc];
            }
        } else {
#pragma unroll
            for (int fc = 0; fc < 4; ++fc) {
                const int col = wc * 64 + fc * 16 + lr;
#pragma unroll
                for (int i = 0; i < 4; ++i)
                    y2[(long)(rb + i) * D + col] = (_Float16)acc[fc][i];
            }
        }
    }
}

// ---------------- wave-per-node aggregate + epilogue (no LDS) ----------------
// out[n] = relu(pre[n] + mean_{e: dst=n} y2[src[e]])   (in-place, pre==out)
// wave: 4 edge-slots x 16 lanes (f16x8 each = full 256B row per slot).
__global__ __launch_bounds__(256) void agg_wave(const _Float16* __restrict__ y2,
                                                const int* __restrict__ offsets,
                                                const int* __restrict__ esrc,
                                                float* __restrict__ out) {
    const int n = blockIdx.x * 4 + (threadIdx.x >> 6);  // node (grid exact)
    const int lane = threadIdx.x & 63;
    const int slot = lane >> 4;   // 0..3
    const int c8 = lane & 15;     // halfs c8*8..+7
    const int s = offsets[n];
    const int e = offsets[n + 1];
    float a[8] = {0.f, 0.f, 0.f, 0.f, 0.f, 0.f, 0.f, 0.f};
    for (int j = s + slot; j < e; j += 4) {
        int sn = esrc[j];
        f16x8 v = *(const f16x8*)&y2[(long)sn * D + c8 * 8];
#pragma unroll
        for (int i = 0; i < 8; ++i) a[i] += (float)v[i];
    }
    // reduce across the 4 slots (lane bits 4,5)
#pragma unroll
    for (int i = 0; i < 8; ++i) {
        a[i] += __shfl_xor(a[i], 16, 64);
        a[i] += __shfl_xor(a[i], 32, 64);
    }
    if (slot == 0) {
        const int deg = e - s;
        const float inv = (deg > 0) ? 1.f / (float)deg : 0.f;
        float4 p0 = *(const float4*)&out[(long)n * D + c8 * 8];
        float4 p1 = *(const float4*)&out[(long)n * D + c8 * 8 + 4];
        float4 o0, o1;
        o0.x = fmaxf(p0.x + a[0] * inv, 0.f);
        o0.y = fmaxf(p0.y + a[1] * inv, 0.f);
        o0.z = fmaxf(p0.z + a[2] * inv, 0.f);
        o0.w = fmaxf(p0.w + a[3] * inv, 0.f);
        o1.x = fmaxf(p1.x + a[4] * inv, 0.f);
        o1.y = fmaxf(p1.y + a[5] * inv, 0.f);
        o1.z = fmaxf(p1.z + a[6] * inv, 0.f);
        o1.w = fmaxf(p1.w + a[7] * inv, 0.f);
        *(float4*)&out[(long)n * D + c8 * 8] = o0;
        *(float4*)&out[(long)n * D + c8 * 8 + 4] = o1;
    }
}

// ---------------- launch ----------------

extern "C" void kernel_launch(void* const* d_in, const int* in_sizes, int n_in,
                              void* d_out, int out_size, void* d_ws, size_t ws_size,
                              hipStream_t stream) {
    const float* x  = (const float*)d_in[0];
    const int* src  = (const int*)d_in[1];
    const int* dst  = (const int*)d_in[2];
    const float* Ws = (const float*)d_in[3];
    const float* Wn = (const float*)d_in[4];
    const float* b  = (const float*)d_in[5];
    float* out = (float*)d_out;

    int* cnt     = (int*)d_ws;                 // N
    int* offsets = cnt + N_NODES;              // N+1
    int* bs      = offsets + N_NODES + 1;      // 128
    int* rank    = bs + 128;                   // E
    int* esrc    = rank + N_EDGES;             // E
    uintptr_t p = (uintptr_t)(esrc + N_EDGES);
    p = (p + 255) & ~(uintptr_t)255;
    _Float16* y2 = (_Float16*)p;               // N*D f16

    const int nblk_scan = (N_NODES + 1023) / 1024;  // 98

    hipMemsetAsync(cnt, 0, N_NODES * sizeof(int), stream);
    hist_rank<<<(N_EDGES + 255) / 256, 256, 0, stream>>>(dst, cnt, rank);
    scan_local<<<nblk_scan, 256, 0, stream>>>(cnt, offsets, bs);
    scan_block2<<<1, 64, 0, stream>>>(bs, offsets, nblk_scan);
    scan_add<<<nblk_scan, 256, 0, stream>>>(offsets, bs);
    scatter2<<<(N_EDGES + 255) / 256, 256, 0, stream>>>(src, dst, offsets, rank, esrc);
    gemm_reg<<<2048, 256, 0, stream>>>(x, Ws, Wn, b, out, y2);
    agg_wave<<<N_NODES / 4, 256, 0, stream>>>(y2, offsets, esrc, out);
}

// Round 11
// 241.849 us; speedup vs baseline: 1.8906x; 1.0428x over previous
//
#include <hip/hip_runtime.h>
#include <stdint.h>

#define N_NODES 100000
#define N_EDGES 800000
#define D 128

typedef _Float16 f16x8 __attribute__((ext_vector_type(8)));
typedef float f32x4 __attribute__((ext_vector_type(4)));

// ---------------- CSR build ----------------

__global__ void hist_rank(const int* __restrict__ dst, int* __restrict__ cnt,
                          int* __restrict__ rank) {
    int e = blockIdx.x * blockDim.x + threadIdx.x;
    if (e < N_EDGES) rank[e] = atomicAdd(&cnt[dst[e]], 1);
}

__global__ void scan_local(const int* __restrict__ cnt, int* __restrict__ offsets,
                           int* __restrict__ bs) {
    __shared__ int sdata[256];
    const int t = threadIdx.x;
    const int base = blockIdx.x * 1024 + t * 4;
    int v[4];
    int s = 0;
#pragma unroll
    for (int j = 0; j < 4; ++j) {
        int i = base + j;
        v[j] = (i < N_NODES) ? cnt[i] : 0;
        s += v[j];
    }
    sdata[t] = s;
    __syncthreads();
    int incl = s;
    for (int off = 1; off < 256; off <<= 1) {
        int add = (t >= off) ? sdata[t - off] : 0;
        __syncthreads();
        incl += add;
        sdata[t] = incl;
        __syncthreads();
    }
    int run = incl - s;
#pragma unroll
    for (int j = 0; j < 4; ++j) {
        int i = base + j;
        if (i < N_NODES) offsets[i] = run;
        run += v[j];
    }
    if (t == 255) bs[blockIdx.x] = incl;
}

__global__ void scan_block2(int* __restrict__ bs, int* __restrict__ offsets, int nblk) {
    int t = threadIdx.x;  // 0..63
    int v0 = (2 * t < nblk) ? bs[2 * t] : 0;
    int v1 = (2 * t + 1 < nblk) ? bs[2 * t + 1] : 0;
    int s = v0 + v1;
    int incl = s;
    for (int off = 1; off < 64; off <<= 1) {
        int n = __shfl_up(incl, off, 64);
        if (t >= off) incl += n;
    }
    int excl = incl - s;
    if (2 * t < nblk) bs[2 * t] = excl;
    if (2 * t + 1 < nblk) bs[2 * t + 1] = excl + v0;
    if (t == 63) offsets[N_NODES] = incl;
}

__global__ void scan_add(int* __restrict__ offsets, const int* __restrict__ bs) {
    const int t = threadIdx.x;
    const int base = blockIdx.x * 1024 + t * 4;
    const int add = bs[blockIdx.x];
#pragma unroll
    for (int j = 0; j < 4; ++j) {
        int i = base + j;
        if (i < N_NODES) offsets[i] += add;
    }
}

__global__ void scatter2(const int* __restrict__ src, const int* __restrict__ dst,
                         const int* __restrict__ offsets, const int* __restrict__ rank,
                         int* __restrict__ esrc) {
    int e = blockIdx.x * blockDim.x + threadIdx.x;
    if (e < N_EDGES) esrc[offsets[dst[e]] + rank[e]] = src[e];
}

// ---------------- register-B MFMA GEMM, double-buffered strips ----------------
// blockIdx.x&1==0: pre = x@Ws + b -> out (fp32);  ==1: y2 = x@Wn -> ws (f16)
__global__ __launch_bounds__(256) void gemm_reg(const float* __restrict__ x,
                                                const float* __restrict__ Ws,
                                                const float* __restrict__ Wn,
                                                const float* __restrict__ bias,
                                                float* __restrict__ pre,
                                                _Float16* __restrict__ y2) {
    const int half = blockIdx.x & 1;
    const int bid = blockIdx.x >> 1;
    const int nb = gridDim.x >> 1;
    const int tid = threadIdx.x;
    const int w = tid >> 6;
    const int lane = tid & 63;
    const int lr = lane & 15;
    const int lk = (lane >> 4) * 8;
    const int wc = w & 1;
    const int ws_ = w >> 1;

    const float* __restrict__ W = half ? Wn : Ws;

    // B fragments: bfrag[ks][fc] covers k = ks*32+lk..+7, col = wc*64+fc*16+lr
    f16x8 bfrag[4][4];
#pragma unroll
    for (int ks = 0; ks < 4; ++ks) {
#pragma unroll
        for (int fc = 0; fc < 4; ++fc) {
            const int col = wc * 64 + fc * 16 + lr;
            const int kb = ks * 32 + lk;
            f16x8 h;
#pragma unroll
            for (int j = 0; j < 8; ++j) h[j] = (_Float16)W[(long)(kb + j) * D + col];
            bfrag[ks][fc] = h;
        }
    }
    float bv[4];
    if (half == 0) {
#pragma unroll
        for (int fc = 0; fc < 4; ++fc) bv[fc] = bias[wc * 64 + fc * 16 + lr];
    }

    auto loadA = [&](f32x4* A, int s) {
        const float* __restrict__ xr = &x[(long)(s * 16 + lr) * D];
#pragma unroll
        for (int ks = 0; ks < 4; ++ks) {
            A[2 * ks] = *(const f32x4*)&xr[ks * 32 + lk];
            A[2 * ks + 1] = *(const f32x4*)&xr[ks * 32 + lk + 4];
        }
    };
    auto compStore = [&](const f32x4* A, int s) {
        f32x4 acc[4];
#pragma unroll
        for (int fc = 0; fc < 4; ++fc) acc[fc] = (f32x4){0.f, 0.f, 0.f, 0.f};
#pragma unroll
        for (int ks = 0; ks < 4; ++ks) {
            f16x8 af;
#pragma unroll
            for (int j = 0; j < 4; ++j) {
                af[j] = (_Float16)A[2 * ks][j];
                af[4 + j] = (_Float16)A[2 * ks + 1][j];
            }
#pragma unroll
            for (int fc = 0; fc < 4; ++fc)
                acc[fc] = __builtin_amdgcn_mfma_f32_16x16x32_f16(af, bfrag[ks][fc],
                                                                 acc[fc], 0, 0, 0);
        }
        const int rb = s * 16 + (lane >> 4) * 4;
        if (half == 0) {
#pragma unroll
            for (int fc = 0; fc < 4; ++fc) {
                const int col = wc * 64 + fc * 16 + lr;
#pragma unroll
                for (int i = 0; i < 4; ++i)
                    pre[(long)(rb + i) * D + col] = acc[fc][i] + bv[fc];
            }
        } else {
#pragma unroll
            for (int fc = 0; fc < 4; ++fc) {
                const int col = wc * 64 + fc * 16 + lr;
#pragma unroll
                for (int i = 0; i < 4; ++i)
                    y2[(long)(rb + i) * D + col] = (_Float16)acc[fc][i];
            }
        }
    };

    const int nstrip = N_NODES / 16;  // 6250, exact
    const int stride = nb * 2;
    int s = bid * 2 + ws_;
    int snext = s + stride;

    f32x4 A0[8], A1[8];
    loadA(A0, s);
    while (true) {
        bool hn = snext < nstrip;
        if (hn) loadA(A1, snext);
        compStore(A0, s);
        if (!hn) break;
        s = snext;
        snext += stride;
        hn = snext < nstrip;
        if (hn) loadA(A0, snext);
        compStore(A1, s);
        if (!hn) break;
        s = snext;
        snext += stride;
    }
}

// ---------------- wave-per-node aggregate + epilogue (no LDS) ----------------
// out[n] = relu(pre[n] + mean_{e: dst=n} y2[src[e]])   (in-place, pre==out)
__global__ __launch_bounds__(256) void agg_wave(const _Float16* __restrict__ y2,
                                                const int* __restrict__ offsets,
                                                const int* __restrict__ esrc,
                                                float* __restrict__ out) {
    const int n = blockIdx.x * 4 + (threadIdx.x >> 6);  // node (grid exact)
    const int lane = threadIdx.x & 63;
    const int slot = lane >> 4;   // 0..3
    const int c8 = lane & 15;     // halfs c8*8..+7
    const int s = offsets[n];
    const int e = offsets[n + 1];
    float a[8] = {0.f, 0.f, 0.f, 0.f, 0.f, 0.f, 0.f, 0.f};
    for (int j = s + slot; j < e; j += 4) {
        int sn = esrc[j];
        f16x8 v = *(const f16x8*)&y2[(long)sn * D + c8 * 8];
#pragma unroll
        for (int i = 0; i < 8; ++i) a[i] += (float)v[i];
    }
#pragma unroll
    for (int i = 0; i < 8; ++i) {
        a[i] += __shfl_xor(a[i], 16, 64);
        a[i] += __shfl_xor(a[i], 32, 64);
    }
    if (slot == 0) {
        const int deg = e - s;
        const float inv = (deg > 0) ? 1.f / (float)deg : 0.f;
        float4 p0 = *(const float4*)&out[(long)n * D + c8 * 8];
        float4 p1 = *(const float4*)&out[(long)n * D + c8 * 8 + 4];
        float4 o0, o1;
        o0.x = fmaxf(p0.x + a[0] * inv, 0.f);
        o0.y = fmaxf(p0.y + a[1] * inv, 0.f);
        o0.z = fmaxf(p0.z + a[2] * inv, 0.f);
        o0.w = fmaxf(p0.w + a[3] * inv, 0.f);
        o1.x = fmaxf(p1.x + a[4] * inv, 0.f);
        o1.y = fmaxf(p1.y + a[5] * inv, 0.f);
        o1.z = fmaxf(p1.z + a[6] * inv, 0.f);
        o1.w = fmaxf(p1.w + a[7] * inv, 0.f);
        *(float4*)&out[(long)n * D + c8 * 8] = o0;
        *(float4*)&out[(long)n * D + c8 * 8 + 4] = o1;
    }
}

// ---------------- launch ----------------

extern "C" void kernel_launch(void* const* d_in, const int* in_sizes, int n_in,
                              void* d_out, int out_size, void* d_ws, size_t ws_size,
                              hipStream_t stream) {
    const float* x  = (const float*)d_in[0];
    const int* src  = (const int*)d_in[1];
    const int* dst  = (const int*)d_in[2];
    const float* Ws = (const float*)d_in[3];
    const float* Wn = (const float*)d_in[4];
    const float* b  = (const float*)d_in[5];
    float* out = (float*)d_out;

    int* cnt     = (int*)d_ws;                 // N
    int* offsets = cnt + N_NODES;              // N+1
    int* bs      = offsets + N_NODES + 1;      // 128
    int* rank    = bs + 128;                   // E
    int* esrc    = rank + N_EDGES;             // E
    uintptr_t p = (uintptr_t)(esrc + N_EDGES);
    p = (p + 255) & ~(uintptr_t)255;
    _Float16* y2 = (_Float16*)p;               // N*D f16

    const int nblk_scan = (N_NODES + 1023) / 1024;  // 98

    hipMemsetAsync(cnt, 0, N_NODES * sizeof(int), stream);
    hist_rank<<<(N_EDGES + 255) / 256, 256, 0, stream>>>(dst, cnt, rank);
    scan_local<<<nblk_scan, 256, 0, stream>>>(cnt, offsets, bs);
    scan_block2<<<1, 64, 0, stream>>>(bs, offsets, nblk_scan);
    scan_add<<<nblk_scan, 256, 0, stream>>>(offsets, bs);
    scatter2<<<(N_EDGES + 255) / 256, 256, 0, stream>>>(src, dst, offsets, rank, esrc);
    gemm_reg<<<1024, 256, 0, stream>>>(x, Ws, Wn, b, out, y2);
    agg_wave<<<N_NODES / 4, 256, 0, stream>>>(y2, offsets, esrc, out);
}